// Round 3
// baseline (312.123 us; speedup 1.0000x reference)
//
#include <hip/hip_runtime.h>
#include <hip/hip_bf16.h>

#define EMB 512
#define NHEADS 8
#define HD 64
#define SEQ 2048

typedef float f32x4 __attribute__((ext_vector_type(4)));
typedef short short8 __attribute__((ext_vector_type(8)));
typedef unsigned short ushort4_t __attribute__((ext_vector_type(4)));

#define MFMA(a, b, c) __builtin_amdgcn_mfma_f32_16x16x32_bf16((a), (b), (c), 0, 0, 0)

__device__ inline unsigned short f2bf(float f) {
    union { float f; unsigned u; } v; v.f = f;
    unsigned r = v.u + 0x7fffu + ((v.u >> 16) & 1u);   // round-to-nearest-even
    return (unsigned short)(r >> 16);
}

__device__ inline short8 f8_to_bf8(float4 a, float4 b) {
    short8 r;
    r[0] = (short)f2bf(a.x); r[1] = (short)f2bf(a.y);
    r[2] = (short)f2bf(a.z); r[3] = (short)f2bf(a.w);
    r[4] = (short)f2bf(b.x); r[5] = (short)f2bf(b.y);
    r[6] = (short)f2bf(b.z); r[7] = (short)f2bf(b.w);
    return r;
}

// ---------------------------------------------------------------------------
// Kernel 1: per-head QKV projection. grid.x = N*H*(S/64), grid.y = 3 (q,k,v)
// Each block: 4 waves x 16 s-rows, one (n,h). y = x @ W.T via mfma_16x16x32.
// q output is pre-scaled by log2(e)/8 (softmax scale folded in, exp2 domain).
// v output is written TRANSPOSED: vt[n][h][d][s].
// ---------------------------------------------------------------------------
__global__ __launch_bounds__(256) void qkv_proj_kernel(
    const float* __restrict__ vin, const float* __restrict__ kin,
    const float* __restrict__ qin,
    const float* __restrict__ Wv, const float* __restrict__ Wk,
    const float* __restrict__ Wq,
    unsigned short* __restrict__ q_ws, unsigned short* __restrict__ k_ws,
    unsigned short* __restrict__ vt_ws)
{
    const int z = blockIdx.y;
    const float* __restrict__ x = (z == 0) ? qin : (z == 1 ? kin : vin);
    const float* __restrict__ W = (z == 0) ? Wq : (z == 1 ? Wk : Wv);

    const int bid = blockIdx.x;
    const int st = bid & 31;            // S/64 = 32 tiles
    const int h  = (bid >> 5) & 7;
    const int n  = bid >> 8;

    const int lane = threadIdx.x & 63;
    const int w    = threadIdx.x >> 6;
    const int lo = lane & 15, hi = lane >> 4;
    const int s_base = st * 64 + w * 16;

    // A fragments: 16 rows (lane lo) x 64 k, 8 contiguous fp32 -> bf16 per kb
    const float* xr = x + ((size_t)n * SEQ + s_base + lo) * EMB + h * HD;
    short8 a[2];
#pragma unroll
    for (int kb = 0; kb < 2; ++kb) {
        const float4* p = (const float4*)(xr + kb * 32 + hi * 8);
        a[kb] = f8_to_bf8(p[0], p[1]);
    }
    // B fragments: B[k=j][n=i] = W[i][j]  (row i of W, contiguous j)
    short8 b[2][4];
#pragma unroll
    for (int nb = 0; nb < 4; ++nb) {
        const float* wr = W + (lo + 16 * nb) * HD;
#pragma unroll
        for (int kb = 0; kb < 2; ++kb) {
            const float4* p = (const float4*)(wr + kb * 32 + hi * 8);
            b[kb][nb] = f8_to_bf8(p[0], p[1]);
        }
    }
    f32x4 acc[4];
#pragma unroll
    for (int nb = 0; nb < 4; ++nb) {
        f32x4 t = {0.f, 0.f, 0.f, 0.f};
        t = MFMA(a[0], b[0][nb], t);
        t = MFMA(a[1], b[1][nb], t);
        acc[nb] = t;
    }
    const size_t nh = (size_t)n * NHEADS + h;
    if (z < 2) {
        const float sc = (z == 0) ? 0.18033688011112042f : 1.0f; // log2(e)/8
        unsigned short* o = (z == 0 ? q_ws : k_ws) + nh * SEQ * HD;
#pragma unroll
        for (int nb = 0; nb < 4; ++nb)
#pragma unroll
            for (int i = 0; i < 4; ++i)
                o[(size_t)(s_base + hi * 4 + i) * HD + lo + 16 * nb] =
                    f2bf(acc[nb][i] * sc);
    } else {
        // transposed store: vt[d][s], 4 consecutive s per lane -> 8B store
        unsigned short* o = vt_ws + nh * HD * SEQ;
#pragma unroll
        for (int nb = 0; nb < 4; ++nb) {
            ushort4_t pk;
            pk[0] = f2bf(acc[nb][0]); pk[1] = f2bf(acc[nb][1]);
            pk[2] = f2bf(acc[nb][2]); pk[3] = f2bf(acc[nb][3]);
            *(ushort4_t*)(o + (size_t)(lo + 16 * nb) * SEQ + s_base + hi * 4) = pk;
        }
    }
}

// ---------------------------------------------------------------------------
// Kernel 2: Wo fp32 -> bf16 (done once, avoids per-block reconversion)
// ---------------------------------------------------------------------------
__global__ __launch_bounds__(256) void wconv_kernel(
    const float* __restrict__ Wo, unsigned short* __restrict__ wob)
{
    const int idx = (blockIdx.x * 256 + threadIdx.x) * 8;
    const float4* p = (const float4*)(Wo + idx);
    short8 r = f8_to_bf8(p[0], p[1]);
    *(short8*)(wob + idx) = r;
}

// ---------------------------------------------------------------------------
// Kernel 3: flash attention. 1 wave = 16 q-rows of one (n,h).
// K, V(transposed) read directly from global (L1/L2-resident), no barriers.
// Online softmax in exp2 domain (q pre-scaled). P transposed via per-wave LDS.
// ---------------------------------------------------------------------------
__global__ __launch_bounds__(256) void attn_kernel(
    const unsigned short* __restrict__ q_ws, const unsigned short* __restrict__ k_ws,
    const unsigned short* __restrict__ vt_ws, const int* __restrict__ mask,
    unsigned short* __restrict__ ao_ws)
{
    __shared__ __align__(16) unsigned short plds[4][16][72]; // +8 pad: no bank conflicts

    const int lane = threadIdx.x & 63;
    const int w = threadIdx.x >> 6;
    const int lo = lane & 15, hi = lane >> 4;
    const int wid = blockIdx.x * 4 + w;
    const int qt = wid & 127;          // S/16 = 128 q-tiles
    const int h  = (wid >> 7) & 7;
    const int n  = wid >> 10;
    const size_t nh = (size_t)n * NHEADS + h;

    const unsigned short* qp = q_ws + nh * SEQ * HD;
    const unsigned short* kp = k_ws + nh * SEQ * HD;
    const unsigned short* vp = vt_ws + nh * HD * SEQ;
    const int* mp = mask + (size_t)n * SEQ;

    const int q0 = qt * 16;
    short8 aq[2];
#pragma unroll
    for (int kb = 0; kb < 2; ++kb)
        aq[kb] = *(const short8*)(qp + (size_t)(q0 + lo) * HD + kb * 32 + hi * 8);

    f32x4 o[4];
    float mrow[4], lacc[4];
#pragma unroll
    for (int nb = 0; nb < 4; ++nb) o[nb] = (f32x4){0.f, 0.f, 0.f, 0.f};
#pragma unroll
    for (int i = 0; i < 4; ++i) { mrow[i] = -1e30f; lacc[i] = 0.f; }

    for (int kt = 0; kt < SEQ; kt += 64) {
        // S = Q K^T (exp2 domain, scale folded into q)
        f32x4 e[4];
#pragma unroll
        for (int nb = 0; nb < 4; ++nb) {
            const unsigned short* kr = kp + (size_t)(kt + lo + 16 * nb) * HD + hi * 8;
            short8 bk0 = *(const short8*)(kr);
            short8 bk1 = *(const short8*)(kr + 32);
            f32x4 t = {0.f, 0.f, 0.f, 0.f};
            t = MFMA(aq[0], bk0, t);
            t = MFMA(aq[1], bk1, t);
            e[nb] = t;
        }
        // mask (key-wise)
#pragma unroll
        for (int nb = 0; nb < 4; ++nb) {
            if (mp[kt + lo + 16 * nb] == 0) {
#pragma unroll
                for (int i = 0; i < 4; ++i) e[nb][i] = -1e30f;
            }
        }
        // tile row max (reduce over 16 lanes of each hi-group)
        float mx[4];
#pragma unroll
        for (int i = 0; i < 4; ++i)
            mx[i] = fmaxf(fmaxf(e[0][i], e[1][i]), fmaxf(e[2][i], e[3][i]));
#pragma unroll
        for (int off = 1; off < 16; off <<= 1)
#pragma unroll
            for (int i = 0; i < 4; ++i)
                mx[i] = fmaxf(mx[i], __shfl_xor(mx[i], off));
        // online-softmax update; P -> LDS (bf16) for fragment transpose
#pragma unroll
        for (int i = 0; i < 4; ++i) {
            float nm = fmaxf(mrow[i], mx[i]);
            float al = __builtin_amdgcn_exp2f(mrow[i] - nm);
            mrow[i] = nm;
            float ps = 0.f;
#pragma unroll
            for (int nb = 0; nb < 4; ++nb) {
                float p = __builtin_amdgcn_exp2f(e[nb][i] - nm);
                ps += p;
                plds[w][hi * 4 + i][lo + 16 * nb] = f2bf(p);
            }
            lacc[i] = lacc[i] * al + ps;   // lane-partial l, reduced once at end
#pragma unroll
            for (int nb = 0; nb < 4; ++nb) o[nb][i] *= al;
        }
        // read P back as A-fragments (same-wave DS ops are in-order)
        short8 pa[2];
#pragma unroll
        for (int kb = 0; kb < 2; ++kb)
            pa[kb] = *(const short8*)(&plds[w][lo][kb * 32 + hi * 8]);
        // O += P V  (V transposed in global: contiguous 16B loads)
#pragma unroll
        for (int nb = 0; nb < 4; ++nb) {
            const unsigned short* vr = vp + (size_t)(lo + 16 * nb) * SEQ + kt + hi * 8;
            short8 bv0 = *(const short8*)(vr);
            short8 bv1 = *(const short8*)(vr + 32);
            o[nb] = MFMA(pa[0], bv0, o[nb]);
            o[nb] = MFMA(pa[1], bv1, o[nb]);
        }
    }
    // final l reduction across the 16-lane group + normalize
#pragma unroll
    for (int off = 1; off < 16; off <<= 1)
#pragma unroll
        for (int i = 0; i < 4; ++i)
            lacc[i] += __shfl_xor(lacc[i], off);
    float linv[4];
#pragma unroll
    for (int i = 0; i < 4; ++i) linv[i] = 1.0f / lacc[i];

    unsigned short* op = ao_ws + ((size_t)n * SEQ + q0) * EMB + h * HD;
#pragma unroll
    for (int nb = 0; nb < 4; ++nb)
#pragma unroll
        for (int i = 0; i < 4; ++i)
            op[(size_t)(hi * 4 + i) * EMB + lo + 16 * nb] = f2bf(o[nb][i] * linv[i]);
}

// ---------------------------------------------------------------------------
// Kernel 4: output projection  out = ao @ Wo.T + bo   (fp32 out)
// ---------------------------------------------------------------------------
__global__ __launch_bounds__(256) void out_proj_kernel(
    const unsigned short* __restrict__ ao_ws, const unsigned short* __restrict__ wob,
    const float* __restrict__ bo, float* __restrict__ out)
{
    const int bid = blockIdx.x;
    const int nc = bid & 7;            // EMB/64 = 8 col tiles
    const int mt = bid >> 3;
    const int lane = threadIdx.x & 63;
    const int w = threadIdx.x >> 6;
    const int lo = lane & 15, hi = lane >> 4;
    const int m0 = mt * 64 + w * 16;
    const int e0 = nc * 64;

    f32x4 acc[4];
#pragma unroll
    for (int nb = 0; nb < 4; ++nb) acc[nb] = (f32x4){0.f, 0.f, 0.f, 0.f};

    const unsigned short* ar = ao_ws + (size_t)(m0 + lo) * EMB;
    for (int k0 = 0; k0 < EMB; k0 += 32) {
        short8 a = *(const short8*)(ar + k0 + hi * 8);
#pragma unroll
        for (int nb = 0; nb < 4; ++nb) {
            short8 b = *(const short8*)(wob + (size_t)(e0 + lo + 16 * nb) * EMB + k0 + hi * 8);
            acc[nb] = MFMA(a, b, acc[nb]);
        }
    }
#pragma unroll
    for (int nb = 0; nb < 4; ++nb) {
        float bias = bo[e0 + lo + 16 * nb];
#pragma unroll
        for (int i = 0; i < 4; ++i)
            out[(size_t)(m0 + hi * 4 + i) * EMB + e0 + lo + 16 * nb] = acc[nb][i] + bias;
    }
}

// ---------------------------------------------------------------------------
extern "C" void kernel_launch(void* const* d_in, const int* in_sizes, int n_in,
                              void* d_out, int out_size, void* d_ws, size_t ws_size,
                              hipStream_t stream)
{
    const float* vin = (const float*)d_in[0];
    const float* kin = (const float*)d_in[1];
    const float* qin = (const float*)d_in[2];
    const int*  mask = (const int*)d_in[3];
    const float* Wv  = (const float*)d_in[4];
    const float* Wk  = (const float*)d_in[5];
    const float* Wq  = (const float*)d_in[6];
    const float* Wo  = (const float*)d_in[7];
    const float* bo  = (const float*)d_in[8];
    float* out = (float*)d_out;

    const int N = in_sizes[0] / (SEQ * EMB);   // 4

    char* ws = (char*)d_ws;
    const size_t qkv_bytes = (size_t)N * NHEADS * SEQ * HD * 2;  // 8.39 MB each
    unsigned short* q_ws  = (unsigned short*)(ws);
    unsigned short* k_ws  = (unsigned short*)(ws + qkv_bytes);
    unsigned short* vt_ws = (unsigned short*)(ws + 2 * qkv_bytes);
    unsigned short* ao_ws = (unsigned short*)(ws + 3 * qkv_bytes);
    unsigned short* wob   = (unsigned short*)(ws + 4 * qkv_bytes);

    hipLaunchKernelGGL(wconv_kernel, dim3(EMB * EMB / 2048), dim3(256), 0, stream,
                       Wo, wob);
    hipLaunchKernelGGL(qkv_proj_kernel, dim3(N * NHEADS * (SEQ / 64), 3), dim3(256), 0, stream,
                       vin, kin, qin, Wv, Wk, Wq, q_ws, k_ws, vt_ws);
    hipLaunchKernelGGL(attn_kernel, dim3(N * NHEADS * (SEQ / 16) / 4), dim3(256), 0, stream,
                       q_ws, k_ws, vt_ws, mask, ao_ws);
    hipLaunchKernelGGL(out_proj_kernel, dim3((N * SEQ / 64) * (EMB / 64)), dim3(256), 0, stream,
                       ao_ws, wob, bo, out);
}